// Round 5
// baseline (786.588 us; speedup 1.0000x reference)
//
#include <hip/hip_runtime.h>
#include <hip/hip_bf16.h>

#define ROWS  16384
#define PTOT  1048576
#define NTOTF 1048576.0f
#define EPSF  1e-5f
#define NREP  16                 // stats replication factor (atomic decontention)

typedef __attribute__((ext_vector_type(8))) short short8;   // 8 bf16 (MFMA A/B frag)
typedef __attribute__((ext_vector_type(4))) float floatx4;  // MFMA C/D frag
typedef float f32x4 __attribute__((ext_vector_type(4)));
typedef f32x4 f32x4u __attribute__((aligned(4)));           // 4B-aligned vector load

union FU { float f; unsigned int u; };
union S8U { short8 s8; unsigned int u[4]; };

__device__ __forceinline__ float bfbits2f(unsigned short s) {
    FU fu; fu.u = ((unsigned int)s) << 16; return fu.f;
}
__device__ __forceinline__ unsigned short f2bfbits(float x) {
    FU fu; fu.f = x;
    unsigned int r = fu.u + 0x7FFFu + ((fu.u >> 16) & 1u);  // RNE
    return (unsigned short)(r >> 16);
}
// packed f32x2 -> bf16x2 (v_cvt_pk_bf16_f32 on gfx950; RNE)
__device__ __forceinline__ unsigned int pk_bf16(float lo, float hi) {
#if __has_builtin(__builtin_amdgcn_cvt_pk_bf16_f32)
    auto v = __builtin_amdgcn_cvt_pk_bf16_f32(lo, hi);
    unsigned int u; __builtin_memcpy(&u, &v, 4); return u;
#else
    return (unsigned int)f2bfbits(lo) | ((unsigned int)f2bfbits(hi) << 16);
#endif
}
// bf16 pair (packed in uint) -> two f32: 2 VALU
__device__ __forceinline__ float2 unpk_bf16(unsigned int u) {
    FU lo, hi; lo.u = u << 16; hi.u = u & 0xffff0000u;
    return make_float2(lo.f, hi.f);
}
__device__ __forceinline__ float relu_f(float x) { return x > 0.f ? x : 0.f; }

// ---------------------------------------------------------------------------
// K1: conv0  X[P][67] fp32 -> H[P][64] bf16 (NO bias — cancels in BN).
// Operand-swapped MFMA: A = w0 (persistent), B = X positions.
// K=67 = 2 k-steps + tail frag (quad0 only). Barrier-free main loop.
// ---------------------------------------------------------------------------
__global__ __launch_bounds__(256, 4) void k_conv0(
    const float* __restrict__ X, const float* __restrict__ w0,
    unsigned short* __restrict__ H, float* __restrict__ stats)
{
    __shared__ float sred[64], s2red[64];
    const int tid  = threadIdx.x;
    const int lane = tid & 63;
    const int wid  = tid >> 6;
    const int ln15 = lane & 15;
    const int quad = lane >> 4;
    const int pbase = blockIdx.x * 256 + wid * 64;

    if (tid < 64) { sred[tid] = 0.f; s2red[tid] = 0.f; }
    __syncthreads();

    // A-fragments: weights. m = mt*16+ln15, k = kh*32+quad*8+j (+ tail frag)
    short8 afr[4][3];
#pragma unroll
    for (int mt = 0; mt < 4; ++mt) {
        const float* wr = w0 + (size_t)(mt * 16 + ln15) * 67;
#pragma unroll
        for (int kh = 0; kh < 2; ++kh) {
            f32x4u wa = *reinterpret_cast<const f32x4u*>(wr + kh * 32 + quad * 8);
            f32x4u wb = *reinterpret_cast<const f32x4u*>(wr + kh * 32 + quad * 8 + 4);
            S8U v;
            v.u[0] = pk_bf16(wa[0], wa[1]); v.u[1] = pk_bf16(wa[2], wa[3]);
            v.u[2] = pk_bf16(wb[0], wb[1]); v.u[3] = pk_bf16(wb[2], wb[3]);
            afr[mt][kh] = v.s8;
        }
        S8U t; t.u[0] = 0; t.u[1] = 0; t.u[2] = 0; t.u[3] = 0;
        if (quad == 0) {
            f32x4u tv = *reinterpret_cast<const f32x4u*>(wr + 63);  // cols 63..66
            t.u[0] = pk_bf16(tv[1], tv[2]); t.u[1] = pk_bf16(tv[3], 0.f);
        }
        afr[mt][2] = t.s8;
    }

    floatx4 s[4] = {}, s2[4] = {};
#pragma unroll
    for (int nt = 0; nt < 4; ++nt) {
        const int pos = pbase + nt * 16 + ln15;
        const float* xr = X + (size_t)pos * 67;
        short8 bf0, bf1, bft;
        {
            f32x4u xa = *reinterpret_cast<const f32x4u*>(xr + quad * 8);
            f32x4u xb = *reinterpret_cast<const f32x4u*>(xr + quad * 8 + 4);
            f32x4u xc = *reinterpret_cast<const f32x4u*>(xr + 32 + quad * 8);
            f32x4u xd = *reinterpret_cast<const f32x4u*>(xr + 32 + quad * 8 + 4);
            S8U v0, v1, vt;
            v0.u[0] = pk_bf16(xa[0], xa[1]); v0.u[1] = pk_bf16(xa[2], xa[3]);
            v0.u[2] = pk_bf16(xb[0], xb[1]); v0.u[3] = pk_bf16(xb[2], xb[3]);
            v1.u[0] = pk_bf16(xc[0], xc[1]); v1.u[1] = pk_bf16(xc[2], xc[3]);
            v1.u[2] = pk_bf16(xd[0], xd[1]); v1.u[3] = pk_bf16(xd[2], xd[3]);
            vt.u[0] = 0; vt.u[1] = 0; vt.u[2] = 0; vt.u[3] = 0;
            if (quad == 0) {
                f32x4u tv = *reinterpret_cast<const f32x4u*>(xr + 63);
                vt.u[0] = pk_bf16(tv[1], tv[2]); vt.u[1] = pk_bf16(tv[3], 0.f);
            }
            bf0 = v0.s8; bf1 = v1.s8; bft = vt.s8;
        }
#pragma unroll
        for (int mt = 0; mt < 4; ++mt) {
            floatx4 c = {0.f, 0.f, 0.f, 0.f};
            c = __builtin_amdgcn_mfma_f32_16x16x32_bf16(afr[mt][0], bf0, c, 0, 0, 0);
            c = __builtin_amdgcn_mfma_f32_16x16x32_bf16(afr[mt][1], bf1, c, 0, 0, 0);
            c = __builtin_amdgcn_mfma_f32_16x16x32_bf16(afr[mt][2], bft, c, 0, 0, 0);
            s[mt] += c; s2[mt] += c * c;
            uint2 o;
            o.x = pk_bf16(c[0], c[1]);
            o.y = pk_bf16(c[2], c[3]);
            *reinterpret_cast<uint2*>(&H[(size_t)pos * 64 + mt * 16 + quad * 4]) = o;
        }
    }
    // stats: sum over positions = over ln15 lanes
#pragma unroll
    for (int mt = 0; mt < 4; ++mt)
#pragma unroll
        for (int rg = 0; rg < 4; ++rg) {
            float a = s[mt][rg], b = s2[mt][rg];
            a += __shfl_xor(a, 1, 64); a += __shfl_xor(a, 2, 64);
            a += __shfl_xor(a, 4, 64); a += __shfl_xor(a, 8, 64);
            b += __shfl_xor(b, 1, 64); b += __shfl_xor(b, 2, 64);
            b += __shfl_xor(b, 4, 64); b += __shfl_xor(b, 8, 64);
            if (ln15 == 0) {
                atomicAdd(&sred[mt * 16 + quad * 4 + rg], a);
                atomicAdd(&s2red[mt * 16 + quad * 4 + rg], b);
            }
        }
    __syncthreads();
    const int rep = (blockIdx.x & (NREP - 1)) * 512;
    if (tid < 64) {
        unsafeAtomicAdd(&stats[rep + tid], sred[tid]);
        unsafeAtomicAdd(&stats[rep + 64 + tid], s2red[tid]);
    }
}

// ---------------------------------------------------------------------------
// K2: conv1 64->64 (no bias). Operand-swapped, barrier-free; BN0+relu applied
// in registers with packed conversions. In-place H.
// ---------------------------------------------------------------------------
__global__ __launch_bounds__(256, 4) void k_conv1(
    const unsigned short* __restrict__ Hin, unsigned short* __restrict__ Hout,
    const float* __restrict__ w1, const float* __restrict__ g0,
    const float* __restrict__ be0, float* __restrict__ stats)
{
    __shared__ float als[64], bls[64], sred[64], s2red[64];
    const int tid  = threadIdx.x;
    const int lane = tid & 63;
    const int wid  = tid >> 6;
    const int ln15 = lane & 15;
    const int quad = lane >> 4;
    const int pbase = blockIdx.x * 256 + wid * 64;

    if (tid < 64) {
        float ssum = 0.f, qsum = 0.f;
#pragma unroll
        for (int r = 0; r < NREP; ++r) { ssum += stats[r * 512 + tid]; qsum += stats[r * 512 + 64 + tid]; }
        const float mean = ssum * (1.f / NTOTF);
        const float var  = qsum * (1.f / NTOTF) - mean * mean;
        const float a    = g0[tid] / sqrtf(var + EPSF);
        als[tid] = a; bls[tid] = be0[tid] - mean * a;
        sred[tid] = 0.f; s2red[tid] = 0.f;
    }
    __syncthreads();

    // per-lane BN coeffs, pair-packed: pair j of half kh covers channels
    // kh*32 + quad*8 + 2j, +1
    float2 al[2][4], bl[2][4];
#pragma unroll
    for (int kh = 0; kh < 2; ++kh)
#pragma unroll
        for (int j = 0; j < 4; ++j) {
            const int c = kh * 32 + quad * 8 + 2 * j;
            al[kh][j] = make_float2(als[c], als[c + 1]);
            bl[kh][j] = make_float2(bls[c], bls[c + 1]);
        }

    short8 afr[4][2];
#pragma unroll
    for (int mt = 0; mt < 4; ++mt) {
        const float* wr = w1 + (size_t)(mt * 16 + ln15) * 64;
#pragma unroll
        for (int kh = 0; kh < 2; ++kh) {
            f32x4u wa = *reinterpret_cast<const f32x4u*>(wr + kh * 32 + quad * 8);
            f32x4u wb = *reinterpret_cast<const f32x4u*>(wr + kh * 32 + quad * 8 + 4);
            S8U v;
            v.u[0] = pk_bf16(wa[0], wa[1]); v.u[1] = pk_bf16(wa[2], wa[3]);
            v.u[2] = pk_bf16(wb[0], wb[1]); v.u[3] = pk_bf16(wb[2], wb[3]);
            afr[mt][kh] = v.s8;
        }
    }

    floatx4 s[4] = {}, s2[4] = {};
#pragma unroll
    for (int nt = 0; nt < 4; ++nt) {
        const int pos = pbase + nt * 16 + ln15;
        const uint4 h0 = *reinterpret_cast<const uint4*>(&Hin[(size_t)pos * 64 + quad * 8]);
        const uint4 h1 = *reinterpret_cast<const uint4*>(&Hin[(size_t)pos * 64 + 32 + quad * 8]);
        S8U b0v, b1v;
        {
            const unsigned int hu0[4] = {h0.x, h0.y, h0.z, h0.w};
            const unsigned int hu1[4] = {h1.x, h1.y, h1.z, h1.w};
#pragma unroll
            for (int j = 0; j < 4; ++j) {
                float2 p0 = unpk_bf16(hu0[j]);
                float2 p1 = unpk_bf16(hu1[j]);
                b0v.u[j] = pk_bf16(relu_f(al[0][j].x * p0.x + bl[0][j].x),
                                   relu_f(al[0][j].y * p0.y + bl[0][j].y));
                b1v.u[j] = pk_bf16(relu_f(al[1][j].x * p1.x + bl[1][j].x),
                                   relu_f(al[1][j].y * p1.y + bl[1][j].y));
            }
        }
#pragma unroll
        for (int mt = 0; mt < 4; ++mt) {
            floatx4 c = {0.f, 0.f, 0.f, 0.f};
            c = __builtin_amdgcn_mfma_f32_16x16x32_bf16(afr[mt][0], b0v.s8, c, 0, 0, 0);
            c = __builtin_amdgcn_mfma_f32_16x16x32_bf16(afr[mt][1], b1v.s8, c, 0, 0, 0);
            s[mt] += c; s2[mt] += c * c;
            uint2 o;
            o.x = pk_bf16(c[0], c[1]);
            o.y = pk_bf16(c[2], c[3]);
            *reinterpret_cast<uint2*>(&Hout[(size_t)pos * 64 + mt * 16 + quad * 4]) = o;
        }
    }
#pragma unroll
    for (int mt = 0; mt < 4; ++mt)
#pragma unroll
        for (int rg = 0; rg < 4; ++rg) {
            float a = s[mt][rg], b = s2[mt][rg];
            a += __shfl_xor(a, 1, 64); a += __shfl_xor(a, 2, 64);
            a += __shfl_xor(a, 4, 64); a += __shfl_xor(a, 8, 64);
            b += __shfl_xor(b, 1, 64); b += __shfl_xor(b, 2, 64);
            b += __shfl_xor(b, 4, 64); b += __shfl_xor(b, 8, 64);
            if (ln15 == 0) {
                atomicAdd(&sred[mt * 16 + quad * 4 + rg], a);
                atomicAdd(&s2red[mt * 16 + quad * 4 + rg], b);
            }
        }
    __syncthreads();
    const int rep = (blockIdx.x & (NREP - 1)) * 512;
    if (tid < 64) {
        unsafeAtomicAdd(&stats[rep + 128 + tid], sred[tid]);
        unsafeAtomicAdd(&stats[rep + 192 + tid], s2red[tid]);
    }
}

// ---------------------------------------------------------------------------
// K3: conv2 64->128 (no bias), A = data orientation (max over positions in
// register). BN1+relu packed in registers; max/min monotone-BN trick.
// ---------------------------------------------------------------------------
__global__ __launch_bounds__(256, 4) void k_conv2(
    const unsigned short* __restrict__ H, const float* __restrict__ w2,
    const float* __restrict__ g1, const float* __restrict__ be1,
    float* __restrict__ rowmax, float* __restrict__ rowmin,
    float* __restrict__ stats)
{
    __shared__ float als[64], bls[64], sred[128], s2red[128];
    const int tid  = threadIdx.x;
    const int lane = tid & 63;
    const int wid  = tid >> 6;
    const int ln15 = lane & 15;
    const int quad = lane >> 4;
    const int r0   = blockIdx.x * 4;

    if (tid < 64) {
        float ssum = 0.f, qsum = 0.f;
#pragma unroll
        for (int r = 0; r < NREP; ++r) { ssum += stats[r * 512 + 128 + tid]; qsum += stats[r * 512 + 192 + tid]; }
        const float mean = ssum * (1.f / NTOTF);
        const float var  = qsum * (1.f / NTOTF) - mean * mean;
        const float a    = g1[tid] / sqrtf(var + EPSF);
        als[tid] = a; bls[tid] = be1[tid] - mean * a;
    }
    if (tid < 128) { sred[tid] = 0.f; s2red[tid] = 0.f; }
    __syncthreads();

    float2 al[2][4], bl[2][4];
#pragma unroll
    for (int kh = 0; kh < 2; ++kh)
#pragma unroll
        for (int j = 0; j < 4; ++j) {
            const int c = kh * 32 + quad * 8 + 2 * j;
            al[kh][j] = make_float2(als[c], als[c + 1]);
            bl[kh][j] = make_float2(bls[c], bls[c + 1]);
        }

    const int chHalf = (wid & 1) * 64;
    short8 bfr[4][2];
#pragma unroll
    for (int nt = 0; nt < 4; ++nt) {
        const float* wr = w2 + (size_t)(chHalf + nt * 16 + ln15) * 64;
#pragma unroll
        for (int kh = 0; kh < 2; ++kh) {
            f32x4u wa = *reinterpret_cast<const f32x4u*>(wr + kh * 32 + quad * 8);
            f32x4u wb = *reinterpret_cast<const f32x4u*>(wr + kh * 32 + quad * 8 + 4);
            S8U v;
            v.u[0] = pk_bf16(wa[0], wa[1]); v.u[1] = pk_bf16(wa[2], wa[3]);
            v.u[2] = pk_bf16(wb[0], wb[1]); v.u[3] = pk_bf16(wb[2], wb[3]);
            bfr[nt][kh] = v.s8;
        }
    }

    float s[4] = {0, 0, 0, 0}, s2[4] = {0, 0, 0, 0};
    for (int rr = 0; rr < 2; ++rr) {
        const int prow = r0 + (wid >> 1) * 2 + rr;
        float mx[4] = {-3.4e38f, -3.4e38f, -3.4e38f, -3.4e38f};
        float mn[4] = {3.4e38f, 3.4e38f, 3.4e38f, 3.4e38f};
#pragma unroll
        for (int mt = 0; mt < 4; ++mt) {
            const size_t rowb = (size_t)(prow * 64 + mt * 16 + ln15) * 64;
            const uint4 h0 = *reinterpret_cast<const uint4*>(&H[rowb + quad * 8]);
            const uint4 h1 = *reinterpret_cast<const uint4*>(&H[rowb + 32 + quad * 8]);
            S8U a0v, a1v;
            {
                const unsigned int hu0[4] = {h0.x, h0.y, h0.z, h0.w};
                const unsigned int hu1[4] = {h1.x, h1.y, h1.z, h1.w};
#pragma unroll
                for (int j = 0; j < 4; ++j) {
                    float2 p0 = unpk_bf16(hu0[j]);
                    float2 p1 = unpk_bf16(hu1[j]);
                    a0v.u[j] = pk_bf16(relu_f(al[0][j].x * p0.x + bl[0][j].x),
                                       relu_f(al[0][j].y * p0.y + bl[0][j].y));
                    a1v.u[j] = pk_bf16(relu_f(al[1][j].x * p1.x + bl[1][j].x),
                                       relu_f(al[1][j].y * p1.y + bl[1][j].y));
                }
            }
#pragma unroll
            for (int nt = 0; nt < 4; ++nt) {
                floatx4 c = {0.f, 0.f, 0.f, 0.f};
                c = __builtin_amdgcn_mfma_f32_16x16x32_bf16(a0v.s8, bfr[nt][0], c, 0, 0, 0);
                c = __builtin_amdgcn_mfma_f32_16x16x32_bf16(a1v.s8, bfr[nt][1], c, 0, 0, 0);
#pragma unroll
                for (int rg = 0; rg < 4; ++rg) {
                    const float h = c[rg];
                    mx[nt] = fmaxf(mx[nt], h);
                    mn[nt] = fminf(mn[nt], h);
                    s[nt] += h; s2[nt] += h * h;
                }
            }
        }
#pragma unroll
        for (int nt = 0; nt < 4; ++nt) {
            mx[nt] = fmaxf(mx[nt], __shfl_xor(mx[nt], 16, 64));
            mx[nt] = fmaxf(mx[nt], __shfl_xor(mx[nt], 32, 64));
            mn[nt] = fminf(mn[nt], __shfl_xor(mn[nt], 16, 64));
            mn[nt] = fminf(mn[nt], __shfl_xor(mn[nt], 32, 64));
        }
        if (lane < 16) {
#pragma unroll
            for (int nt = 0; nt < 4; ++nt) {
                rowmax[(size_t)prow * 128 + chHalf + nt * 16 + lane] = mx[nt];
                rowmin[(size_t)prow * 128 + chHalf + nt * 16 + lane] = mn[nt];
            }
        }
    }
#pragma unroll
    for (int nt = 0; nt < 4; ++nt) {
        s[nt]  += __shfl_xor(s[nt], 16, 64);  s[nt]  += __shfl_xor(s[nt], 32, 64);
        s2[nt] += __shfl_xor(s2[nt], 16, 64); s2[nt] += __shfl_xor(s2[nt], 32, 64);
    }
    if (lane < 16) {
#pragma unroll
        for (int nt = 0; nt < 4; ++nt) {
            atomicAdd(&sred[chHalf + nt * 16 + ln15], s[nt]);
            atomicAdd(&s2red[chHalf + nt * 16 + ln15], s2[nt]);
        }
    }
    __syncthreads();
    const int rep = (blockIdx.x & (NREP - 1)) * 512;
    if (tid < 128) {
        unsafeAtomicAdd(&stats[rep + 256 + tid], sred[tid]);
        unsafeAtomicAdd(&stats[rep + 384 + tid], s2red[tid]);
    }
}

// ---------------------------------------------------------------------------
// K4: finalize BN2 + epilogue (b2 also cancels in BN2 -> ignored)
// ---------------------------------------------------------------------------
__global__ __launch_bounds__(256) void k_out(
    const float* __restrict__ rowmax, const float* __restrict__ rowmin,
    const float* __restrict__ g2, const float* __restrict__ be2,
    const float* __restrict__ stats, float* __restrict__ out)
{
    __shared__ float als[128], bls[128];
    const int tid = threadIdx.x;
    if (tid < 128) {
        float ssum = 0.f, qsum = 0.f;
#pragma unroll
        for (int r = 0; r < NREP; ++r) { ssum += stats[r * 512 + 256 + tid]; qsum += stats[r * 512 + 384 + tid]; }
        const float mean = ssum * (1.f / NTOTF);
        const float var  = qsum * (1.f / NTOTF) - mean * mean;
        const float a    = g2[tid] / sqrtf(var + EPSF);
        als[tid] = a; bls[tid] = be2[tid] - mean * a;
    }
    __syncthreads();
    const int idx = blockIdx.x * 256 + tid;
    const int o = idx & 127;
    const float a = als[o];
    const float v = (a > 0.f) ? rowmax[idx] : rowmin[idx];
    out[idx] = relu_f(a * v + bls[o]);
}

// ---------------------------------------------------------------------------
extern "C" void kernel_launch(void* const* d_in, const int* in_sizes, int n_in,
                              void* d_out, int out_size, void* d_ws, size_t ws_size,
                              hipStream_t stream)
{
    (void)in_sizes; (void)n_in; (void)out_size; (void)ws_size;
    const float* X   = (const float*)d_in[0];
    const float* w0  = (const float*)d_in[1];
    const float* g0  = (const float*)d_in[3];
    const float* be0 = (const float*)d_in[4];
    const float* w1  = (const float*)d_in[5];
    const float* g1  = (const float*)d_in[7];
    const float* be1 = (const float*)d_in[8];
    const float* w2  = (const float*)d_in[9];
    const float* g2  = (const float*)d_in[11];
    const float* be2 = (const float*)d_in[12];
    float* out = (float*)d_out;

    char* ws = (char*)d_ws;
    unsigned short* H = (unsigned short*)ws;                 // 134,217,728 B
    float* rowmax = (float*)(ws + 134217728);                // 8,388,608 B
    float* rowmin = (float*)(ws + 134217728 + 8388608);      // 8,388,608 B
    float* stats  = (float*)(ws + 134217728 + 2 * 8388608);  // NREP*512 floats

    hipMemsetAsync(stats, 0, NREP * 512 * sizeof(float), stream);
    hipLaunchKernelGGL(k_conv0, dim3(PTOT / 256), dim3(256), 0, stream, X, w0, H, stats);
    hipLaunchKernelGGL(k_conv1, dim3(PTOT / 256), dim3(256), 0, stream, H, H, w1, g0, be0, stats);
    hipLaunchKernelGGL(k_conv2, dim3(ROWS / 4), dim3(256), 0, stream, H, w2, g1, be1, rowmax, rowmin, stats);
    hipLaunchKernelGGL(k_out, dim3(ROWS * 128 / 256), dim3(256), 0, stream, rowmax, rowmin, g2, be2, stats, out);
}

// Round 6
// 628.664 us; speedup vs baseline: 1.2512x; 1.2512x over previous
//
#include <hip/hip_runtime.h>
#include <hip/hip_bf16.h>

#define ROWS  16384
#define PTOT  1048576
#define NTOTF 1048576.0f
#define EPSF  1e-5f
#define NREP  16                 // stats replication factor (atomic decontention)

typedef __attribute__((ext_vector_type(8))) short short8;   // 8 bf16 (MFMA A/B frag)
typedef __attribute__((ext_vector_type(4))) float floatx4;  // MFMA C/D frag
typedef float f32x4 __attribute__((ext_vector_type(4)));
typedef f32x4 f32x4u __attribute__((aligned(4)));           // 4B-aligned vector load

union FU { float f; unsigned int u; };
union S8U { short8 s8; unsigned int u[4]; };

__device__ __forceinline__ unsigned short f2bfbits(float x) {
    FU fu; fu.f = x;
    unsigned int r = fu.u + 0x7FFFu + ((fu.u >> 16) & 1u);  // RNE
    return (unsigned short)(r >> 16);
}
__device__ __forceinline__ unsigned int pk_bf16(float lo, float hi) {
#if __has_builtin(__builtin_amdgcn_cvt_pk_bf16_f32)
    auto v = __builtin_amdgcn_cvt_pk_bf16_f32(lo, hi);
    unsigned int u; __builtin_memcpy(&u, &v, 4); return u;
#else
    return (unsigned int)f2bfbits(lo) | ((unsigned int)f2bfbits(hi) << 16);
#endif
}
__device__ __forceinline__ float2 unpk_bf16(unsigned int u) {
    FU lo, hi; lo.u = u << 16; hi.u = u & 0xffff0000u;
    return make_float2(lo.f, hi.f);
}
__device__ __forceinline__ float relu_f(float x) { return x > 0.f ? x : 0.f; }

// async global->LDS, 16 B per lane; lds dst = wave-uniform base + lane*16
__device__ __forceinline__ void async16(const float4* g, float* l) {
    __builtin_amdgcn_global_load_lds(
        (const __attribute__((address_space(1))) void*)(g),
        (__attribute__((address_space(3))) void*)(l), 16, 0, 0);
}

// XOR swizzle: global chunk a lane fetches so that row r's logical 16B chunk c
// lands at LDS slot r*8 + (c ^ (r&7))  (for 128B rows = 8 chunks).
__device__ __forceinline__ int lane_perm(int lane) {
    return (lane & 56) | ((lane & 7) ^ ((lane >> 3) & 7));
}

// ---------------------------------------------------------------------------
// K1: conv0  X[P][67] fp32 -> H0[P][64] bf16 (no bias — cancels in BN).
// 128 positions/block staged flat into LDS via global_load_lds (34,304 B, 9
// wave-instrs of 16B/lane -> high MLP, zero VGPR cost). One barrier, then
// operand-swapped MFMA (A=weights) + direct uint2 stores. Stats replicated.
// ---------------------------------------------------------------------------
__global__ __launch_bounds__(256, 4) void k_conv0(
    const float* __restrict__ X, const float* __restrict__ w0,
    unsigned short* __restrict__ H0, float* __restrict__ stats)
{
    __shared__ alignas(16) float Xs[128 * 67];   // 34,304 B, rows 268 B (natural bank stagger)
    __shared__ float sred[64], s2red[64];
    const int tid  = threadIdx.x;
    const int lane = tid & 63;
    const int wid  = tid >> 6;
    const int ln15 = lane & 15;
    const int quad = lane >> 4;
    const int p0   = blockIdx.x * 128;

    if (tid < 64) { sred[tid] = 0.f; s2red[tid] = 0.f; }

    // stage X flat: 2144 float4 chunks, 9 iterations (last partial, exec-masked)
    const float4* Xv = (const float4*)(X + (size_t)p0 * 67);
#pragma unroll
    for (int i = 0; i < 9; ++i) {
        const int idx = i * 256 + tid;
        if (idx < 2144)
            async16(&Xv[idx], &Xs[(i * 256 + wid * 64) * 4]);
    }

    // A-fragments: weights. m = mt*16+ln15, k = kh*32+quad*8+j (+ tail frag)
    short8 afr[4][3];
#pragma unroll
    for (int mt = 0; mt < 4; ++mt) {
        const float* wr = w0 + (size_t)(mt * 16 + ln15) * 67;
#pragma unroll
        for (int kh = 0; kh < 2; ++kh) {
            f32x4u wa = *reinterpret_cast<const f32x4u*>(wr + kh * 32 + quad * 8);
            f32x4u wb = *reinterpret_cast<const f32x4u*>(wr + kh * 32 + quad * 8 + 4);
            S8U v;
            v.u[0] = pk_bf16(wa[0], wa[1]); v.u[1] = pk_bf16(wa[2], wa[3]);
            v.u[2] = pk_bf16(wb[0], wb[1]); v.u[3] = pk_bf16(wb[2], wb[3]);
            afr[mt][kh] = v.s8;
        }
        S8U t; t.u[0] = 0; t.u[1] = 0; t.u[2] = 0; t.u[3] = 0;
        if (quad == 0) {
            f32x4u tv = *reinterpret_cast<const f32x4u*>(wr + 63);  // cols 63..66
            t.u[0] = pk_bf16(tv[1], tv[2]); t.u[1] = pk_bf16(tv[3], 0.f);
        }
        afr[mt][2] = t.s8;
    }
    __syncthreads();   // drains async loads + orders sred init

    floatx4 s[4] = {}, s2[4] = {};
#pragma unroll
    for (int nt = 0; nt < 2; ++nt) {
        const int posl = wid * 32 + nt * 16 + ln15;
        const float* xr = &Xs[posl * 67];
        short8 bf0, bf1, bft;
        {
            f32x4u xa = *reinterpret_cast<const f32x4u*>(xr + quad * 8);
            f32x4u xb = *reinterpret_cast<const f32x4u*>(xr + quad * 8 + 4);
            f32x4u xc = *reinterpret_cast<const f32x4u*>(xr + 32 + quad * 8);
            f32x4u xd = *reinterpret_cast<const f32x4u*>(xr + 32 + quad * 8 + 4);
            S8U v0, v1, vt;
            v0.u[0] = pk_bf16(xa[0], xa[1]); v0.u[1] = pk_bf16(xa[2], xa[3]);
            v0.u[2] = pk_bf16(xb[0], xb[1]); v0.u[3] = pk_bf16(xb[2], xb[3]);
            v1.u[0] = pk_bf16(xc[0], xc[1]); v1.u[1] = pk_bf16(xc[2], xc[3]);
            v1.u[2] = pk_bf16(xd[0], xd[1]); v1.u[3] = pk_bf16(xd[2], xd[3]);
            vt.u[0] = 0; vt.u[1] = 0; vt.u[2] = 0; vt.u[3] = 0;
            if (quad == 0) {
                f32x4u tv = *reinterpret_cast<const f32x4u*>(xr + 63);
                vt.u[0] = pk_bf16(tv[1], tv[2]); vt.u[1] = pk_bf16(tv[3], 0.f);
            }
            bf0 = v0.s8; bf1 = v1.s8; bft = vt.s8;
        }
#pragma unroll
        for (int mt = 0; mt < 4; ++mt) {
            floatx4 c = {0.f, 0.f, 0.f, 0.f};
            c = __builtin_amdgcn_mfma_f32_16x16x32_bf16(afr[mt][0], bf0, c, 0, 0, 0);
            c = __builtin_amdgcn_mfma_f32_16x16x32_bf16(afr[mt][1], bf1, c, 0, 0, 0);
            c = __builtin_amdgcn_mfma_f32_16x16x32_bf16(afr[mt][2], bft, c, 0, 0, 0);
            s[mt] += c; s2[mt] += c * c;
            uint2 o;
            o.x = pk_bf16(c[0], c[1]);
            o.y = pk_bf16(c[2], c[3]);
            *reinterpret_cast<uint2*>(&H0[(size_t)(p0 + posl) * 64 + mt * 16 + quad * 4]) = o;
        }
    }
#pragma unroll
    for (int mt = 0; mt < 4; ++mt)
#pragma unroll
        for (int rg = 0; rg < 4; ++rg) {
            float a = s[mt][rg], b = s2[mt][rg];
            a += __shfl_xor(a, 1, 64); a += __shfl_xor(a, 2, 64);
            a += __shfl_xor(a, 4, 64); a += __shfl_xor(a, 8, 64);
            b += __shfl_xor(b, 1, 64); b += __shfl_xor(b, 2, 64);
            b += __shfl_xor(b, 4, 64); b += __shfl_xor(b, 8, 64);
            if (ln15 == 0) {
                atomicAdd(&sred[mt * 16 + quad * 4 + rg], a);
                atomicAdd(&s2red[mt * 16 + quad * 4 + rg], b);
            }
        }
    __syncthreads();
    const int rep = (blockIdx.x & (NREP - 1)) * 512;
    if (tid < 64) {
        unsafeAtomicAdd(&stats[rep + tid], sred[tid]);
        unsafeAtomicAdd(&stats[rep + 64 + tid], s2red[tid]);
    }
}

// ---------------------------------------------------------------------------
// K2: conv1 64->64. 256 positions/block (32 KB) staged via global_load_lds
// with XOR bank swizzle; one barrier; BN0+relu in registers; H1 to a
// separate buffer.
// ---------------------------------------------------------------------------
__global__ __launch_bounds__(256, 4) void k_conv1(
    const unsigned short* __restrict__ H0, unsigned short* __restrict__ H1,
    const float* __restrict__ w1, const float* __restrict__ g0,
    const float* __restrict__ be0, float* __restrict__ stats)
{
    __shared__ alignas(16) unsigned short Hs[256 * 64];   // 32,768 B
    __shared__ float als[64], bls[64], sred[64], s2red[64];
    const int tid  = threadIdx.x;
    const int lane = tid & 63;
    const int wid  = tid >> 6;
    const int ln15 = lane & 15;
    const int quad = lane >> 4;

    if (tid < 64) {
        float ssum = 0.f, qsum = 0.f;
#pragma unroll
        for (int r = 0; r < NREP; ++r) { ssum += stats[r * 512 + tid]; qsum += stats[r * 512 + 64 + tid]; }
        const float mean = ssum * (1.f / NTOTF);
        const float var  = qsum * (1.f / NTOTF) - mean * mean;
        const float a    = g0[tid] / sqrtf(var + EPSF);
        als[tid] = a; bls[tid] = be0[tid] - mean * a;
        sred[tid] = 0.f; s2red[tid] = 0.f;
    }

    // stage 2048 16B chunks, XOR-swizzled on the global side
    uint4* HsV = (uint4*)Hs;
    const uint4* Hv = (const uint4*)(H0 + (size_t)blockIdx.x * 256 * 64);
    const int lp = lane_perm(lane);
#pragma unroll
    for (int i = 0; i < 8; ++i) {
        const int cb = i * 256 + wid * 64;   // wave-uniform chunk base
        async16((const float4*)&Hv[cb + lp], (float*)&HsV[cb]);
    }

    short8 afr[4][2];
#pragma unroll
    for (int mt = 0; mt < 4; ++mt) {
        const float* wr = w1 + (size_t)(mt * 16 + ln15) * 64;
#pragma unroll
        for (int kh = 0; kh < 2; ++kh) {
            f32x4u wa = *reinterpret_cast<const f32x4u*>(wr + kh * 32 + quad * 8);
            f32x4u wb = *reinterpret_cast<const f32x4u*>(wr + kh * 32 + quad * 8 + 4);
            S8U v;
            v.u[0] = pk_bf16(wa[0], wa[1]); v.u[1] = pk_bf16(wa[2], wa[3]);
            v.u[2] = pk_bf16(wb[0], wb[1]); v.u[3] = pk_bf16(wb[2], wb[3]);
            afr[mt][kh] = v.s8;
        }
    }
    __syncthreads();

    float2 al[2][4], bl[2][4];
#pragma unroll
    for (int kh = 0; kh < 2; ++kh)
#pragma unroll
        for (int j = 0; j < 4; ++j) {
            const int c = kh * 32 + quad * 8 + 2 * j;
            al[kh][j] = make_float2(als[c], als[c + 1]);
            bl[kh][j] = make_float2(bls[c], bls[c + 1]);
        }

    floatx4 s[4] = {}, s2[4] = {};
#pragma unroll
    for (int nt = 0; nt < 4; ++nt) {
        const int row = wid * 64 + nt * 16 + ln15;  // position within block tile
        const int r7 = row & 7;
        const uint4 h0 = HsV[row * 8 + (quad ^ r7)];
        const uint4 h1 = HsV[row * 8 + ((quad + 4) ^ r7)];
        S8U b0v, b1v;
        {
            const unsigned int hu0[4] = {h0.x, h0.y, h0.z, h0.w};
            const unsigned int hu1[4] = {h1.x, h1.y, h1.z, h1.w};
#pragma unroll
            for (int j = 0; j < 4; ++j) {
                float2 p0 = unpk_bf16(hu0[j]);
                float2 p1 = unpk_bf16(hu1[j]);
                b0v.u[j] = pk_bf16(relu_f(al[0][j].x * p0.x + bl[0][j].x),
                                   relu_f(al[0][j].y * p0.y + bl[0][j].y));
                b1v.u[j] = pk_bf16(relu_f(al[1][j].x * p1.x + bl[1][j].x),
                                   relu_f(al[1][j].y * p1.y + bl[1][j].y));
            }
        }
        const size_t pg = (size_t)blockIdx.x * 256 + row;
#pragma unroll
        for (int mt = 0; mt < 4; ++mt) {
            floatx4 c = {0.f, 0.f, 0.f, 0.f};
            c = __builtin_amdgcn_mfma_f32_16x16x32_bf16(afr[mt][0], b0v.s8, c, 0, 0, 0);
            c = __builtin_amdgcn_mfma_f32_16x16x32_bf16(afr[mt][1], b1v.s8, c, 0, 0, 0);
            s[mt] += c; s2[mt] += c * c;
            uint2 o;
            o.x = pk_bf16(c[0], c[1]);
            o.y = pk_bf16(c[2], c[3]);
            *reinterpret_cast<uint2*>(&H1[pg * 64 + mt * 16 + quad * 4]) = o;
        }
    }
#pragma unroll
    for (int mt = 0; mt < 4; ++mt)
#pragma unroll
        for (int rg = 0; rg < 4; ++rg) {
            float a = s[mt][rg], b = s2[mt][rg];
            a += __shfl_xor(a, 1, 64); a += __shfl_xor(a, 2, 64);
            a += __shfl_xor(a, 4, 64); a += __shfl_xor(a, 8, 64);
            b += __shfl_xor(b, 1, 64); b += __shfl_xor(b, 2, 64);
            b += __shfl_xor(b, 4, 64); b += __shfl_xor(b, 8, 64);
            if (ln15 == 0) {
                atomicAdd(&sred[mt * 16 + quad * 4 + rg], a);
                atomicAdd(&s2red[mt * 16 + quad * 4 + rg], b);
            }
        }
    __syncthreads();
    const int rep = (blockIdx.x & (NREP - 1)) * 512;
    if (tid < 64) {
        unsafeAtomicAdd(&stats[rep + 128 + tid], sred[tid]);
        unsafeAtomicAdd(&stats[rep + 192 + tid], s2red[tid]);
    }
}

// ---------------------------------------------------------------------------
// K3: conv2 64->128. One wave per point-row computing ALL 128 channels (no
// duplicate H reads). Staged via global_load_lds + swizzle; BN1+relu in
// registers; max/min monotone-BN trick; H2 never materialized.
// ---------------------------------------------------------------------------
__global__ __launch_bounds__(256, 2) void k_conv2(
    const unsigned short* __restrict__ H1, const float* __restrict__ w2,
    const float* __restrict__ g1, const float* __restrict__ be1,
    float* __restrict__ rowmax, float* __restrict__ rowmin,
    float* __restrict__ stats)
{
    __shared__ alignas(16) unsigned short Hs[256 * 64];   // 32,768 B (4 prows)
    __shared__ float als[64], bls[64], sred[128], s2red[128];
    const int tid  = threadIdx.x;
    const int lane = tid & 63;
    const int wid  = tid >> 6;
    const int ln15 = lane & 15;
    const int quad = lane >> 4;

    if (tid < 64) {
        float ssum = 0.f, qsum = 0.f;
#pragma unroll
        for (int r = 0; r < NREP; ++r) { ssum += stats[r * 512 + 128 + tid]; qsum += stats[r * 512 + 192 + tid]; }
        const float mean = ssum * (1.f / NTOTF);
        const float var  = qsum * (1.f / NTOTF) - mean * mean;
        const float a    = g1[tid] / sqrtf(var + EPSF);
        als[tid] = a; bls[tid] = be1[tid] - mean * a;
    }
    if (tid < 128) { sred[tid] = 0.f; s2red[tid] = 0.f; }

    uint4* HsV = (uint4*)Hs;
    const uint4* Hv = (const uint4*)(H1 + (size_t)blockIdx.x * 256 * 64);
    const int lp = lane_perm(lane);
#pragma unroll
    for (int i = 0; i < 8; ++i) {
        const int cb = i * 256 + wid * 64;
        async16((const float4*)&Hv[cb + lp], (float*)&HsV[cb]);
    }

    // B-fragments: all 128 output channels per wave (A = data orientation)
    short8 bfr[8][2];
#pragma unroll
    for (int nt = 0; nt < 8; ++nt) {
        const float* wr = w2 + (size_t)(nt * 16 + ln15) * 64;
#pragma unroll
        for (int kh = 0; kh < 2; ++kh) {
            f32x4u wa = *reinterpret_cast<const f32x4u*>(wr + kh * 32 + quad * 8);
            f32x4u wb = *reinterpret_cast<const f32x4u*>(wr + kh * 32 + quad * 8 + 4);
            S8U v;
            v.u[0] = pk_bf16(wa[0], wa[1]); v.u[1] = pk_bf16(wa[2], wa[3]);
            v.u[2] = pk_bf16(wb[0], wb[1]); v.u[3] = pk_bf16(wb[2], wb[3]);
            bfr[nt][kh] = v.s8;
        }
    }
    __syncthreads();

    float2 al[2][4], bl[2][4];
#pragma unroll
    for (int kh = 0; kh < 2; ++kh)
#pragma unroll
        for (int j = 0; j < 4; ++j) {
            const int c = kh * 32 + quad * 8 + 2 * j;
            al[kh][j] = make_float2(als[c], als[c + 1]);
            bl[kh][j] = make_float2(bls[c], bls[c + 1]);
        }

    float mx[8], mn[8], s[8], s2[8];
#pragma unroll
    for (int nt = 0; nt < 8; ++nt) { mx[nt] = -3.4e38f; mn[nt] = 3.4e38f; s[nt] = 0.f; s2[nt] = 0.f; }

#pragma unroll
    for (int mt = 0; mt < 4; ++mt) {
        const int row = wid * 64 + mt * 16 + ln15;
        const int r7 = row & 7;
        const uint4 h0 = HsV[row * 8 + (quad ^ r7)];
        const uint4 h1 = HsV[row * 8 + ((quad + 4) ^ r7)];
        S8U a0v, a1v;
        {
            const unsigned int hu0[4] = {h0.x, h0.y, h0.z, h0.w};
            const unsigned int hu1[4] = {h1.x, h1.y, h1.z, h1.w};
#pragma unroll
            for (int j = 0; j < 4; ++j) {
                float2 p0 = unpk_bf16(hu0[j]);
                float2 p1 = unpk_bf16(hu1[j]);
                a0v.u[j] = pk_bf16(relu_f(al[0][j].x * p0.x + bl[0][j].x),
                                   relu_f(al[0][j].y * p0.y + bl[0][j].y));
                a1v.u[j] = pk_bf16(relu_f(al[1][j].x * p1.x + bl[1][j].x),
                                   relu_f(al[1][j].y * p1.y + bl[1][j].y));
            }
        }
#pragma unroll
        for (int nt = 0; nt < 8; ++nt) {
            floatx4 c = {0.f, 0.f, 0.f, 0.f};
            c = __builtin_amdgcn_mfma_f32_16x16x32_bf16(a0v.s8, bfr[nt][0], c, 0, 0, 0);
            c = __builtin_amdgcn_mfma_f32_16x16x32_bf16(a1v.s8, bfr[nt][1], c, 0, 0, 0);
#pragma unroll
            for (int rg = 0; rg < 4; ++rg) {
                const float h = c[rg];
                mx[nt] = fmaxf(mx[nt], h);
                mn[nt] = fminf(mn[nt], h);
                s[nt] += h; s2[nt] += h * h;
            }
        }
    }
#pragma unroll
    for (int nt = 0; nt < 8; ++nt) {
        mx[nt] = fmaxf(mx[nt], __shfl_xor(mx[nt], 16, 64));
        mx[nt] = fmaxf(mx[nt], __shfl_xor(mx[nt], 32, 64));
        mn[nt] = fminf(mn[nt], __shfl_xor(mn[nt], 16, 64));
        mn[nt] = fminf(mn[nt], __shfl_xor(mn[nt], 32, 64));
        s[nt]  += __shfl_xor(s[nt], 16, 64);  s[nt]  += __shfl_xor(s[nt], 32, 64);
        s2[nt] += __shfl_xor(s2[nt], 16, 64); s2[nt] += __shfl_xor(s2[nt], 32, 64);
    }
    const size_t prow = (size_t)blockIdx.x * 4 + wid;
    if (lane < 16) {
#pragma unroll
        for (int nt = 0; nt < 8; ++nt) {
            rowmax[prow * 128 + nt * 16 + lane] = mx[nt];
            rowmin[prow * 128 + nt * 16 + lane] = mn[nt];
            atomicAdd(&sred[nt * 16 + lane], s[nt]);
            atomicAdd(&s2red[nt * 16 + lane], s2[nt]);
        }
    }
    __syncthreads();
    const int rep = (blockIdx.x & (NREP - 1)) * 512;
    if (tid < 128) {
        unsafeAtomicAdd(&stats[rep + 256 + tid], sred[tid]);
        unsafeAtomicAdd(&stats[rep + 384 + tid], s2red[tid]);
    }
}

// ---------------------------------------------------------------------------
// K4: finalize BN2 + epilogue (b2 cancels in BN2 -> ignored)
// ---------------------------------------------------------------------------
__global__ __launch_bounds__(256) void k_out(
    const float* __restrict__ rowmax, const float* __restrict__ rowmin,
    const float* __restrict__ g2, const float* __restrict__ be2,
    const float* __restrict__ stats, float* __restrict__ out)
{
    __shared__ float als[128], bls[128];
    const int tid = threadIdx.x;
    if (tid < 128) {
        float ssum = 0.f, qsum = 0.f;
#pragma unroll
        for (int r = 0; r < NREP; ++r) { ssum += stats[r * 512 + 256 + tid]; qsum += stats[r * 512 + 384 + tid]; }
        const float mean = ssum * (1.f / NTOTF);
        const float var  = qsum * (1.f / NTOTF) - mean * mean;
        const float a    = g2[tid] / sqrtf(var + EPSF);
        als[tid] = a; bls[tid] = be2[tid] - mean * a;
    }
    __syncthreads();
    const int idx = blockIdx.x * 256 + tid;
    const int o = idx & 127;
    const float a = als[o];
    const float v = (a > 0.f) ? rowmax[idx] : rowmin[idx];
    out[idx] = relu_f(a * v + bls[o]);
}

// ---------------------------------------------------------------------------
extern "C" void kernel_launch(void* const* d_in, const int* in_sizes, int n_in,
                              void* d_out, int out_size, void* d_ws, size_t ws_size,
                              hipStream_t stream)
{
    (void)in_sizes; (void)n_in; (void)out_size; (void)ws_size;
    const float* X   = (const float*)d_in[0];
    const float* w0  = (const float*)d_in[1];
    const float* g0  = (const float*)d_in[3];
    const float* be0 = (const float*)d_in[4];
    const float* w1  = (const float*)d_in[5];
    const float* g1  = (const float*)d_in[7];
    const float* be1 = (const float*)d_in[8];
    const float* w2  = (const float*)d_in[9];
    const float* g2  = (const float*)d_in[11];
    const float* be2 = (const float*)d_in[12];
    float* out = (float*)d_out;

    char* ws = (char*)d_ws;
    unsigned short* H0 = (unsigned short*)ws;                      // 134,217,728 B
    unsigned short* H1 = (unsigned short*)(ws + 134217728);        // 134,217,728 B
    float* rowmax = (float*)(ws + 2 * 134217728);                  // 8,388,608 B
    float* rowmin = (float*)(ws + 2 * 134217728 + 8388608);        // 8,388,608 B
    float* stats  = (float*)(ws + 2 * 134217728 + 2 * 8388608);    // NREP*512 floats

    hipMemsetAsync(stats, 0, NREP * 512 * sizeof(float), stream);
    hipLaunchKernelGGL(k_conv0, dim3(PTOT / 128), dim3(256), 0, stream, X, w0, H0, stats);
    hipLaunchKernelGGL(k_conv1, dim3(PTOT / 256), dim3(256), 0, stream, H0, H1, w1, g0, be0, stats);
    hipLaunchKernelGGL(k_conv2, dim3(ROWS / 4), dim3(256), 0, stream, H1, w2, g1, be1, rowmax, rowmin, stats);
    hipLaunchKernelGGL(k_out, dim3(ROWS * 128 / 256), dim3(256), 0, stream, rowmax, rowmin, g2, be2, stats, out);
}